// Round 2
// baseline (171.450 us; speedup 1.0000x reference)
//
#include <hip/hip_runtime.h>

// KL(p||q) for diagonal Gaussians, reduced to a single scalar:
// out = (0.5/B) * sum_{b,d} [ (qlv-plv) + exp(plv-qlv) + (pmu-qmu)^2*exp(-qlv) - 1 ]
// Memory-latency-bound reduction over 4 x 32MB fp32 arrays.
// No grid-stride loop: each thread loads 2 float4 per array, all 8 loads
// issued before any compute so latency is fully overlapped.

__device__ __forceinline__ float kl4(const float4 a, const float4 b,
                                     const float4 c, const float4 d) {
  float acc = 0.0f, lr, dx;
  lr = d.x - b.x; dx = a.x - c.x;
  acc += lr + __expf(-lr) + dx * dx * __expf(-d.x) - 1.0f;
  lr = d.y - b.y; dx = a.y - c.y;
  acc += lr + __expf(-lr) + dx * dx * __expf(-d.y) - 1.0f;
  lr = d.z - b.z; dx = a.z - c.z;
  acc += lr + __expf(-lr) + dx * dx * __expf(-d.z) - 1.0f;
  lr = d.w - b.w; dx = a.w - c.w;
  acc += lr + __expf(-lr) + dx * dx * __expf(-d.w) - 1.0f;
  return acc;
}

__global__ __launch_bounds__(256) void kl_reduce_kernel(
    const float4* __restrict__ pmu,
    const float4* __restrict__ plv,
    const float4* __restrict__ qmu,
    const float4* __restrict__ qlv,
    float* __restrict__ out,
    int n4, float scale) {
  const int half = n4 >> 1;
  const int i0 = blockIdx.x * blockDim.x + threadIdx.x;
  float acc = 0.0f;
  if (i0 < half) {
    const int i1 = i0 + half;
    // Issue all 8 loads before any use — 8 independent loads in flight.
    const float4 a0 = pmu[i0];
    const float4 b0 = plv[i0];
    const float4 c0 = qmu[i0];
    const float4 d0 = qlv[i0];
    const float4 a1 = pmu[i1];
    const float4 b1 = plv[i1];
    const float4 c1 = qmu[i1];
    const float4 d1 = qlv[i1];
    acc = kl4(a0, b0, c0, d0) + kl4(a1, b1, c1, d1);
  }

  // wave-64 butterfly reduce
  #pragma unroll
  for (int off = 32; off > 0; off >>= 1)
    acc += __shfl_down(acc, off, 64);

  __shared__ float sm[4];  // 256 threads / 64 lanes = 4 waves
  const int lane = threadIdx.x & 63;
  const int wid  = threadIdx.x >> 6;
  if (lane == 0) sm[wid] = acc;
  __syncthreads();
  if (threadIdx.x == 0) {
    const float blocksum = sm[0] + sm[1] + sm[2] + sm[3];
    atomicAdd(out, blocksum * scale);  // device-scope by default on CDNA
  }
}

extern "C" void kernel_launch(void* const* d_in, const int* in_sizes, int n_in,
                              void* d_out, int out_size, void* d_ws, size_t ws_size,
                              hipStream_t stream) {
  const float* pmu = (const float*)d_in[0];
  const float* plv = (const float*)d_in[1];
  const float* qmu = (const float*)d_in[2];
  const float* qlv = (const float*)d_in[3];
  float* out = (float*)d_out;

  const int n = in_sizes[0];            // 16384*512 = 8388608
  const int B = 16384;
  const int n4 = n / 4;                 // 2097152 float4 per array
  const float scale = 0.5f / (float)B;

  // d_out is poisoned to 0xAA before every launch; zero it on-stream.
  hipMemsetAsync(d_out, 0, sizeof(float), stream);

  const int block = 256;
  const int half = n4 / 2;              // 1048576 threads needed
  const int grid = (half + block - 1) / block;  // 4096 blocks
  kl_reduce_kernel<<<grid, block, 0, stream>>>(
      (const float4*)pmu, (const float4*)plv, (const float4*)qmu,
      (const float4*)qlv, out, n4, scale);
}

// Round 3
// 149.592 us; speedup vs baseline: 1.1461x; 1.1461x over previous
//
#include <hip/hip_runtime.h>

// KL(p||q) for diagonal Gaussians, reduced to a single scalar:
// out = (0.5/B) * sum_{b,d} [ (qlv-plv) + exp(plv-qlv) + (pmu-qmu)^2*exp(-qlv) - 1 ]
//
// Two-stage reduction: stage 1 writes one partial per block (plain store, NO
// atomics — a same-address device-scope atomicAdd tail was costing ~9 ns/block
// serialized: 2048 blocks -> 46us, 4096 blocks -> 65us). Stage 2 (1 block)
// folds the partials and writes d_out directly (no memset needed).

__device__ __forceinline__ float kl4(const float4 a, const float4 b,
                                     const float4 c, const float4 d) {
  float acc = 0.0f, lr, dx;
  lr = d.x - b.x; dx = a.x - c.x;
  acc += lr + __expf(-lr) + dx * dx * __expf(-d.x) - 1.0f;
  lr = d.y - b.y; dx = a.y - c.y;
  acc += lr + __expf(-lr) + dx * dx * __expf(-d.y) - 1.0f;
  lr = d.z - b.z; dx = a.z - c.z;
  acc += lr + __expf(-lr) + dx * dx * __expf(-d.z) - 1.0f;
  lr = d.w - b.w; dx = a.w - c.w;
  acc += lr + __expf(-lr) + dx * dx * __expf(-d.w) - 1.0f;
  return acc;
}

__device__ __forceinline__ float block_reduce_256(float acc) {
  #pragma unroll
  for (int off = 32; off > 0; off >>= 1)
    acc += __shfl_down(acc, off, 64);
  __shared__ float sm[4];
  const int lane = threadIdx.x & 63;
  const int wid  = threadIdx.x >> 6;
  if (lane == 0) sm[wid] = acc;
  __syncthreads();
  return sm[0] + sm[1] + sm[2] + sm[3];  // valid in all threads after sync
}

// Stage 1: 2048 blocks x 256 threads; each thread handles 4 float4 per array
// (contiguous grid-stride pattern), depth-2 software pipeline for MLP.
__global__ __launch_bounds__(256) void kl_partial_kernel(
    const float4* __restrict__ pmu,
    const float4* __restrict__ plv,
    const float4* __restrict__ qmu,
    const float4* __restrict__ qlv,
    float* __restrict__ partials) {
  const int stride = gridDim.x * blockDim.x;      // 524288
  const int i0 = blockIdx.x * blockDim.x + threadIdx.x;
  const int i1 = i0 + stride;
  const int i2 = i1 + stride;
  const int i3 = i2 + stride;

  // Pipeline: loads for slot k+1 issued before compute of slot k.
  float4 a0 = pmu[i0], b0 = plv[i0], c0 = qmu[i0], d0 = qlv[i0];
  float4 a1 = pmu[i1], b1 = plv[i1], c1 = qmu[i1], d1 = qlv[i1];
  float acc = kl4(a0, b0, c0, d0);
  a0 = pmu[i2]; b0 = plv[i2]; c0 = qmu[i2]; d0 = qlv[i2];
  acc += kl4(a1, b1, c1, d1);
  a1 = pmu[i3]; b1 = plv[i3]; c1 = qmu[i3]; d1 = qlv[i3];
  acc += kl4(a0, b0, c0, d0);
  acc += kl4(a1, b1, c1, d1);

  const float blocksum = block_reduce_256(acc);
  if (threadIdx.x == 0) partials[blockIdx.x] = blocksum;
}

// Stage 2: single block folds nparts partials, scales, writes the scalar.
__global__ __launch_bounds__(256) void kl_final_kernel(
    const float* __restrict__ partials, float* __restrict__ out,
    int nparts, float scale) {
  float acc = 0.0f;
  for (int i = threadIdx.x; i < nparts; i += 256) acc += partials[i];
  const float total = block_reduce_256(acc);
  if (threadIdx.x == 0) out[0] = total * scale;
}

extern "C" void kernel_launch(void* const* d_in, const int* in_sizes, int n_in,
                              void* d_out, int out_size, void* d_ws, size_t ws_size,
                              hipStream_t stream) {
  const float4* pmu = (const float4*)d_in[0];
  const float4* plv = (const float4*)d_in[1];
  const float4* qmu = (const float4*)d_in[2];
  const float4* qlv = (const float4*)d_in[3];
  float* out = (float*)d_out;
  float* partials = (float*)d_ws;       // 2048 floats = 8 KB scratch

  const int B = 16384;
  const float scale = 0.5f / (float)B;

  const int block = 256;
  const int grid = 2048;                // n4 = 2M float4/array = grid*block*4
  kl_partial_kernel<<<grid, block, 0, stream>>>(pmu, plv, qmu, qlv, partials);
  kl_final_kernel<<<1, block, 0, stream>>>(partials, out, grid, scale);
}

// Round 5
// 145.910 us; speedup vs baseline: 1.1750x; 1.0252x over previous
//
#include <hip/hip_runtime.h>

// KL(p||q) for diagonal Gaussians, reduced to a single scalar:
// out = (0.5/B) * sum_{b,d} [ (qlv-plv) + exp(plv-qlv) + (pmu-qmu)^2*exp(-qlv) - 1 ]
//
// Two-stage reduction. Stage 1 history: compiler kept collapsing software
// pipelines to VGPR=32 (~4 loads in flight) -> latency-bound at ~3 TB/s
// delivered. This version forces all 16 loads (4 tiers x 4 arrays) into
// explicit register arrays with nontemporal loads before any compute.
// Note: __builtin_nontemporal_load needs a native vector type, not HIP float4.

typedef float vf4 __attribute__((ext_vector_type(4)));

__device__ __forceinline__ float kl4(const vf4 a, const vf4 b,
                                     const vf4 c, const vf4 d) {
  float acc = 0.0f, lr, dx;
  #pragma unroll
  for (int k = 0; k < 4; ++k) {
    lr = d[k] - b[k];
    dx = a[k] - c[k];
    acc += lr + __expf(-lr) + dx * dx * __expf(-d[k]) - 1.0f;
  }
  return acc;
}

__device__ __forceinline__ float block_reduce_256(float acc) {
  #pragma unroll
  for (int off = 32; off > 0; off >>= 1)
    acc += __shfl_down(acc, off, 64);
  __shared__ float sm[4];
  const int lane = threadIdx.x & 63;
  const int wid  = threadIdx.x >> 6;
  if (lane == 0) sm[wid] = acc;
  __syncthreads();
  return sm[0] + sm[1] + sm[2] + sm[3];
}

// Stage 1: 2048 blocks x 256 threads; each thread loads 4 vf4 per array
// (16 loads total), ALL issued before any compute.
__global__ __launch_bounds__(256) void kl_partial_kernel(
    const vf4* __restrict__ pmu,
    const vf4* __restrict__ plv,
    const vf4* __restrict__ qmu,
    const vf4* __restrict__ qlv,
    float* __restrict__ partials) {
  const int stride = gridDim.x * blockDim.x;      // 524288
  const int base = blockIdx.x * blockDim.x + threadIdx.x;

  vf4 A[4], Bv[4], C[4], Dv[4];
  #pragma unroll
  for (int t = 0; t < 4; ++t) {
    const int i = base + t * stride;
    A[t]  = __builtin_nontemporal_load(&pmu[i]);
    Bv[t] = __builtin_nontemporal_load(&plv[i]);
    C[t]  = __builtin_nontemporal_load(&qmu[i]);
    Dv[t] = __builtin_nontemporal_load(&qlv[i]);
  }

  float acc = 0.0f;
  #pragma unroll
  for (int t = 0; t < 4; ++t)
    acc += kl4(A[t], Bv[t], C[t], Dv[t]);

  const float blocksum = block_reduce_256(acc);
  if (threadIdx.x == 0) partials[blockIdx.x] = blocksum;
}

// Stage 2: single block folds nparts partials, scales, writes the scalar.
__global__ __launch_bounds__(256) void kl_final_kernel(
    const float* __restrict__ partials, float* __restrict__ out,
    int nparts, float scale) {
  float acc = 0.0f;
  for (int i = threadIdx.x; i < nparts; i += 256) acc += partials[i];
  const float total = block_reduce_256(acc);
  if (threadIdx.x == 0) out[0] = total * scale;
}

extern "C" void kernel_launch(void* const* d_in, const int* in_sizes, int n_in,
                              void* d_out, int out_size, void* d_ws, size_t ws_size,
                              hipStream_t stream) {
  const vf4* pmu = (const vf4*)d_in[0];
  const vf4* plv = (const vf4*)d_in[1];
  const vf4* qmu = (const vf4*)d_in[2];
  const vf4* qlv = (const vf4*)d_in[3];
  float* out = (float*)d_out;
  float* partials = (float*)d_ws;       // 2048 floats = 8 KB scratch

  const int B = 16384;
  const float scale = 0.5f / (float)B;

  const int block = 256;
  const int grid = 2048;                // n4 = 2M vf4/array = grid*block*4
  kl_partial_kernel<<<grid, block, 0, stream>>>(pmu, plv, qmu, qlv, partials);
  kl_final_kernel<<<1, block, 0, stream>>>(partials, out, grid, scale);
}

// Round 6
// 142.716 us; speedup vs baseline: 1.2013x; 1.0224x over previous
//
#include <hip/hip_runtime.h>

// KL(p||q) for diagonal Gaussians, reduced to a single scalar:
// out = (0.5/B) * sum_{b,d} [ (qlv-plv) + exp(plv-qlv) + (pmu-qmu)^2*exp(-qlv) - 1 ]
//
// Two-stage reduction. History: MLP (16 loads in flight, NT) didn't move the
// ~40us floor -> not latency-bound. All prior versions used 8MB-apart tier
// strides (16 scattered streams per wave, ~256/CU) -> suspected HBM row/TLB
// thrash capping delivered BW at ~3.3 TB/s (fill kernel: 6.6 TB/s).
// This version: each block reads one CONTIGUOUS 16KB window per array
// (tier stride = 256 float4 inside the window) -> 4 sequential streams/block.

typedef float vf4 __attribute__((ext_vector_type(4)));

__device__ __forceinline__ float kl4(const vf4 a, const vf4 b,
                                     const vf4 c, const vf4 d) {
  float acc = 0.0f, lr, dx;
  #pragma unroll
  for (int k = 0; k < 4; ++k) {
    lr = d[k] - b[k];
    dx = a[k] - c[k];
    acc += lr + __expf(-lr) + dx * dx * __expf(-d[k]) - 1.0f;
  }
  return acc;
}

__device__ __forceinline__ float block_reduce_256(float acc) {
  #pragma unroll
  for (int off = 32; off > 0; off >>= 1)
    acc += __shfl_down(acc, off, 64);
  __shared__ float sm[4];
  const int lane = threadIdx.x & 63;
  const int wid  = threadIdx.x >> 6;
  if (lane == 0) sm[wid] = acc;
  __syncthreads();
  return sm[0] + sm[1] + sm[2] + sm[3];
}

// Stage 1: 2048 blocks x 256 threads. Block b owns vf4 range
// [b*1024, (b+1)*1024) in each array (16KB contiguous window); thread reads
// tiers at +256 within the window. All 16 loads issued before any compute.
__global__ __launch_bounds__(256) void kl_partial_kernel(
    const vf4* __restrict__ pmu,
    const vf4* __restrict__ plv,
    const vf4* __restrict__ qmu,
    const vf4* __restrict__ qlv,
    float* __restrict__ partials) {
  const int base = blockIdx.x * 1024 + threadIdx.x;

  vf4 A[4], Bv[4], C[4], Dv[4];
  #pragma unroll
  for (int t = 0; t < 4; ++t) {
    const int i = base + t * 256;
    A[t]  = __builtin_nontemporal_load(&pmu[i]);
    Bv[t] = __builtin_nontemporal_load(&plv[i]);
    C[t]  = __builtin_nontemporal_load(&qmu[i]);
    Dv[t] = __builtin_nontemporal_load(&qlv[i]);
  }

  float acc = 0.0f;
  #pragma unroll
  for (int t = 0; t < 4; ++t)
    acc += kl4(A[t], Bv[t], C[t], Dv[t]);

  const float blocksum = block_reduce_256(acc);
  if (threadIdx.x == 0) partials[blockIdx.x] = blocksum;
}

// Stage 2: single block folds nparts partials, scales, writes the scalar.
__global__ __launch_bounds__(256) void kl_final_kernel(
    const float* __restrict__ partials, float* __restrict__ out,
    int nparts, float scale) {
  float acc = 0.0f;
  for (int i = threadIdx.x; i < nparts; i += 256) acc += partials[i];
  const float total = block_reduce_256(acc);
  if (threadIdx.x == 0) out[0] = total * scale;
}

extern "C" void kernel_launch(void* const* d_in, const int* in_sizes, int n_in,
                              void* d_out, int out_size, void* d_ws, size_t ws_size,
                              hipStream_t stream) {
  const vf4* pmu = (const vf4*)d_in[0];
  const vf4* plv = (const vf4*)d_in[1];
  const vf4* qmu = (const vf4*)d_in[2];
  const vf4* qlv = (const vf4*)d_in[3];
  float* out = (float*)d_out;
  float* partials = (float*)d_ws;       // 2048 floats = 8 KB scratch

  const int B = 16384;
  const float scale = 0.5f / (float)B;

  const int block = 256;
  const int grid = 2048;                // 2048 * 1024 vf4 = 2M vf4 per array
  kl_partial_kernel<<<grid, block, 0, stream>>>(pmu, plv, qmu, qlv, partials);
  kl_final_kernel<<<1, block, 0, stream>>>(partials, out, grid, scale);
}